// Round 7
// baseline (744.863 us; speedup 1.0000x reference)
//
#include <hip/hip_runtime.h>
#include <hip/hip_bf16.h>

typedef float f32x4 __attribute__((ext_vector_type(4)));
typedef short bfx8 __attribute__((ext_vector_type(8)));   // 8 bf16 in 4 VGPRs

typedef const __attribute__((address_space(1))) void* gvp;
typedef __attribute__((address_space(3))) void* lvp;

static __device__ __forceinline__ unsigned short f2bf(float f) {
    return __builtin_bit_cast(unsigned short, __float2bfloat16(f));
}

static __device__ __forceinline__ ushort4 cvt4(f32x4 v) {
    return make_ushort4(f2bf(v[0]), f2bf(v[1]), f2bf(v[2]), f2bf(v[3]));
}

// ---------------------------------------------------------------------------
// Kernel 0: cast + transpose weights into WcatT[768][768] bf16.
// ---------------------------------------------------------------------------
__global__ void prep_w(const float* __restrict__ Wk, const float* __restrict__ Wq,
                       const float* __restrict__ Wv, unsigned short* __restrict__ WT) {
    const int n = blockIdx.x;       // 0..767
    const int e = threadIdx.x;      // 0..767
    const int which = n >> 8;
    const int h = n & 255;
    const float* W = (which == 0) ? Wq : (which == 1) ? Wk : Wv;
    WT[(size_t)n * 768 + e] = f2bf(W[(size_t)e * 256 + h]);
}

// ---------------------------------------------------------------------------
// Kernel 1: QKV = X @ [Wq|Wk|Wv].  256x256 tile, 8 waves (2M x 4N), BK=64,
// double-buffered 128KB LDS, 2-phase pipeline.
// ROUND 6 FIX: __launch_bounds__(512, 1).  Round 5's (512,2) forced a
// 128-VGPR cap -> accumulator spill to scratch (measured: 1.28GB WRITE_SIZE,
// 908MB FETCH, MfmaUtil 4%). This kernel needs ~240 VGPR; at 128KB LDS the
// natural occupancy is 1 block/CU (= 2 waves/SIMD) anyway.
// ---------------------------------------------------------------------------
__global__ __launch_bounds__(512, 1) void qkv_gemm(const float* __restrict__ X,
                                                   const unsigned short* __restrict__ WT,
                                                   unsigned short* __restrict__ QKV) {
    __shared__ __align__(16) char LDS[131072];

    const int tid = threadIdx.x;
    const int bid = blockIdx.x;                    // 0..767
    const int l   = (bid & 7) * 96 + (bid >> 3);   // bijective XCD remap (768%8==0)
    const int bn  = l % 3;                         // 0=Q 1=K 2=V
    const int bm  = l / 3;                         // 0..255
    const int m0 = bm * 256;
    const int n0 = bn * 256;
    const int w = tid >> 6, lane = tid & 63;
    const int wr = w >> 2, wc = w & 3;             // 2M x 4N wave grid
    const int lrow = lane & 15, lhi = lane >> 4;
    const bool vswap = (bn == 2);

    f32x4 acc[8][4];
    const f32x4 zero = {0.f, 0.f, 0.f, 0.f};
#pragma unroll
    for (int i = 0; i < 8; ++i)
#pragma unroll
        for (int j = 0; j < 4; ++j) acc[i][j] = zero;

    f32x4 areg[8];

    // ---- A: coalesced reg load (16 lanes x float4 = contiguous 256B/row-seg)
#define STAGE_A_LOAD(kt)                                                       \
    {                                                                          \
        const int k0s = (kt) * 64;                                             \
        _Pragma("unroll")                                                      \
        for (int i = 0; i < 8; ++i) {                                          \
            const int f = i * 512 + tid;                                       \
            const int row = f >> 4, col = (f & 15) * 4;                        \
            areg[i] = *(const f32x4*)(X + (size_t)(m0 + row) * 768 + k0s + col); \
        }                                                                      \
    }
    // ---- A: cvt + swizzled ds_write_b64 into Ab[bs] (rows 128B)
#define STAGE_A_WRITE(bs)                                                      \
    {                                                                          \
        _Pragma("unroll")                                                      \
        for (int i = 0; i < 8; ++i) {                                          \
            const int f = i * 512 + tid;                                       \
            const int row = f >> 4;                                            \
            const int cb  = (f & 15) * 8;                                      \
            const int cbs = cb ^ ((row & 7) << 4);                             \
            *(ushort4*)(LDS + (bs) * 32768 + row * 128 + cbs) = cvt4(areg[i]); \
        }                                                                      \
    }
    // ---- B: global_load_lds w16, linear dest, inverse-swizzled source
#define STAGE_B(kt, bs)                                                        \
    {                                                                          \
        const int k0s = (kt) * 64;                                             \
        _Pragma("unroll")                                                      \
        for (int i = 0; i < 4; ++i) {                                          \
            const int f = i * 512 + tid;                                       \
            const int row = f >> 3;                                            \
            const int cb  = (f & 7) * 16;                                      \
            const int cbs = cb ^ ((row & 7) << 4);                             \
            const unsigned short* g = WT + (size_t)(n0 + row) * 768 + k0s + (cbs >> 1); \
            char* lp = LDS + 65536 + (bs) * 32768 + i * 8192 + w * 1024;       \
            __builtin_amdgcn_global_load_lds((gvp)g, (lvp)lp, 16, 0, 0);       \
        }                                                                      \
    }

    // prologue
    STAGE_B(0, 0);
    STAGE_A_LOAD(0);
    STAGE_A_WRITE(0);
    __syncthreads();

    int cur = 0;
    for (int kt = 0; kt < 12; ++kt) {
        if (kt < 11) {
            STAGE_B(kt + 1, cur ^ 1);
            STAGE_A_LOAD(kt + 1);
        }
#pragma unroll
        for (int kk = 0; kk < 2; ++kk) {
            const int kb2 = (kk * 32 + lhi * 8) * 2;       // byte col in 128B row
            bfx8 a[8], bb4[4];
#pragma unroll
            for (int ni = 0; ni < 4; ++ni) {
                const int brow = wc * 64 + ni * 16 + lrow;
                bb4[ni] = *(const bfx8*)(LDS + 65536 + cur * 32768 + brow * 128 +
                                         (kb2 ^ ((brow & 7) << 4)));
            }
#pragma unroll
            for (int mi = 0; mi < 8; ++mi) {
                const int arow = wr * 128 + mi * 16 + lrow;
                a[mi] = *(const bfx8*)(LDS + cur * 32768 + arow * 128 +
                                       (kb2 ^ ((arow & 7) << 4)));
            }
            if (!vswap) {
#pragma unroll
                for (int mi = 0; mi < 8; ++mi)
#pragma unroll
                    for (int ni = 0; ni < 4; ++ni)
                        acc[mi][ni] = __builtin_amdgcn_mfma_f32_16x16x32_bf16(
                            a[mi], bb4[ni], acc[mi][ni], 0, 0, 0);
            } else {
#pragma unroll
                for (int mi = 0; mi < 8; ++mi)
#pragma unroll
                    for (int ni = 0; ni < 4; ++ni)
                        acc[mi][ni] = __builtin_amdgcn_mfma_f32_16x16x32_bf16(
                            bb4[ni], a[mi], acc[mi][ni], 0, 0, 0);   // D[n][m]
            }
        }
        if (kt < 11) STAGE_A_WRITE(cur ^ 1);
        __syncthreads();   // drains B DMA + A ds_writes; releases buffer cur
        cur ^= 1;
    }

    // ---- epilogue: fragments -> swizzled LDS C[256 rows][512B], then
    //      coalesced global stores. Row swizzle: byte ^= (row&7)<<4.
    if (!vswap) {
        // C row = trel (m), col = h*2 bytes
#pragma unroll
        for (int mi = 0; mi < 8; ++mi)
#pragma unroll
            for (int ni = 0; ni < 4; ++ni) {
                const int h2 = (wc * 64 + ni * 16 + lrow) * 2;
#pragma unroll
                for (int j = 0; j < 4; ++j) {
                    const int trel = wr * 128 + mi * 16 + lhi * 4 + j;
                    *(unsigned short*)(LDS + trel * 512 + (h2 ^ ((trel & 7) << 4))) =
                        f2bf(acc[mi][ni][j]);
                }
            }
    } else {
        // C row = h (n), col = trel*2 bytes  (V' = [h][t])
#pragma unroll
        for (int mi = 0; mi < 8; ++mi)
#pragma unroll
            for (int ni = 0; ni < 4; ++ni) {
                const int t2 = (wr * 128 + mi * 16 + lrow) * 2;
#pragma unroll
                for (int j = 0; j < 4; ++j) {
                    const int h = wc * 64 + ni * 16 + lhi * 4 + j;
                    *(unsigned short*)(LDS + h * 512 + (t2 ^ ((h & 7) << 4))) =
                        f2bf(acc[mi][ni][j]);
                }
            }
    }
    __syncthreads();

    // coalesced read-out: 16B/lane chunks, 128B per 16 consecutive lanes
#pragma unroll
    for (int i = 0; i < 16; ++i) {
        const int f = i * 512 + tid;
        const int r  = f >> 5;            // LDS row (trel for Q/K, h for V)
        const int c8 = (f & 31) * 8;      // element offset in row (0..248)
        const bfx8 v = *(const bfx8*)(LDS + r * 512 + ((c8 * 2) ^ ((r & 7) << 4)));
        if (bn < 2) {
            const int b = bm * 2 + (r >> 7);
            unsigned short* g = QKV + (((size_t)(b * 3 + bn)) << 15) +
                                (size_t)(r & 127) * 256 + c8;
            *(bfx8*)g = v;
        } else {
            const int b = bm * 2 + (c8 >> 7);
            unsigned short* g = QKV + (((size_t)(b * 3 + 2)) << 15) +
                                (size_t)r * 128 + (c8 & 127);
            *(bfx8*)g = v;
        }
    }
}

// ---------------------------------------------------------------------------
// Kernel 2: per-batch causal attention (unchanged — passing).
// ---------------------------------------------------------------------------
__global__ __launch_bounds__(512) void attn(const unsigned short* __restrict__ QKV,
                                            float* __restrict__ Out) {
    __shared__ unsigned short Kl[128][264];
    __shared__ unsigned short Vt[256][136];

    const int b = blockIdx.x;
    const int tid = threadIdx.x;
    const int w = tid >> 6, lane = tid & 63;
    const int lrow = lane & 15, lhi = lane >> 4;

    const unsigned short* Qb = QKV + ((size_t)(b * 3 + 0) << 15);
    const unsigned short* Kb = QKV + ((size_t)(b * 3 + 1) << 15);
    const unsigned short* Vb = QKV + ((size_t)(b * 3 + 2) << 15);

    const int t0 = w * 16;
    bfx8 aq[8];
#pragma unroll
    for (int kk = 0; kk < 8; ++kk)
        aq[kk] = *(const bfx8*)(Qb + (size_t)(t0 + lrow) * 256 + kk * 32 + lhi * 8);

#pragma unroll
    for (int i = 0; i < 8; ++i) {
        int f = i * 512 + tid;
        {
            int row = f >> 5, c = (f & 31) * 8;
            *(bfx8*)&Kl[row][c] = *(const bfx8*)(Kb + (size_t)row * 256 + c);
        }
        {
            int row = f >> 4, c = (f & 15) * 8;
            *(bfx8*)&Vt[row][c] = *(const bfx8*)(Vb + (size_t)row * 128 + c);
        }
    }
    __syncthreads();

    f32x4 sacc[8];
    const f32x4 zero = {0.f, 0.f, 0.f, 0.f};
#pragma unroll
    for (int sj = 0; sj < 8; ++sj) sacc[sj] = zero;
#pragma unroll
    for (int kk = 0; kk < 8; ++kk) {
        const int kb = kk * 32 + lhi * 8;
#pragma unroll
        for (int sj = 0; sj < 8; ++sj) {
            bfx8 bk = *(const bfx8*)&Kl[sj * 16 + lrow][kb];
            sacc[sj] = __builtin_amdgcn_mfma_f32_16x16x32_bf16(aq[kk], bk, sacc[sj], 0, 0, 0);
        }
    }

    const float scale = 0.03608439182435161f;   // 1/sqrt(768)
    float inv[4];
#pragma unroll
    for (int j = 0; j < 4; ++j) {
        const int t = t0 + lhi * 4 + j;
        float m = -1e30f;
#pragma unroll
        for (int sj = 0; sj < 8; ++sj) {
            int s = sj * 16 + lrow;
            float vv = sacc[sj][j] * scale;
            vv = (s <= t) ? vv : -1e30f;
            sacc[sj][j] = vv;
            m = fmaxf(m, vv);
        }
#pragma unroll
        for (int d = 1; d < 16; d <<= 1) m = fmaxf(m, __shfl_xor(m, d));
        float sum = 0.f;
#pragma unroll
        for (int sj = 0; sj < 8; ++sj) {
            float e = __expf(sacc[sj][j] - m);
            sacc[sj][j] = e;
            sum += e;
        }
#pragma unroll
        for (int d = 1; d < 16; d <<= 1) sum += __shfl_xor(sum, d);
        inv[j] = 1.0f / sum;
    }

    __syncthreads();

    unsigned short* Pl = &Kl[0][0] + (size_t)w * (16 * 136);
#pragma unroll
    for (int sj = 0; sj < 8; ++sj)
#pragma unroll
        for (int j = 0; j < 4; ++j)
            Pl[(lhi * 4 + j) * 136 + sj * 16 + lrow] = f2bf(sacc[sj][j] * inv[j]);

    bfx8 pa[4];
#pragma unroll
    for (int kk = 0; kk < 4; ++kk)
        pa[kk] = *(const bfx8*)(Pl + lrow * 136 + kk * 32 + lhi * 8);

    f32x4 oacc[16];
#pragma unroll
    for (int ni = 0; ni < 16; ++ni) oacc[ni] = zero;
#pragma unroll
    for (int ni = 0; ni < 16; ++ni) {
#pragma unroll
        for (int kk = 0; kk < 4; ++kk) {
            bfx8 bv = *(const bfx8*)&Vt[ni * 16 + lrow][kk * 32 + lhi * 8];
            oacc[ni] = __builtin_amdgcn_mfma_f32_16x16x32_bf16(pa[kk], bv, oacc[ni], 0, 0, 0);
        }
    }

    float* Ob = Out + (size_t)b * 128 * 256;
#pragma unroll
    for (int ni = 0; ni < 16; ++ni) {
#pragma unroll
        for (int j = 0; j < 4; ++j) {
            const int t = t0 + lhi * 4 + j;
            const int h = ni * 16 + lrow;
            Ob[(size_t)t * 256 + h] = oacc[ni][j];
        }
    }
}

// ---------------------------------------------------------------------------
extern "C" void kernel_launch(void* const* d_in, const int* in_sizes, int n_in,
                              void* d_out, int out_size, void* d_ws, size_t ws_size,
                              hipStream_t stream) {
    (void)in_sizes; (void)n_in; (void)out_size; (void)ws_size;
    const float* X  = (const float*)d_in[0];   // res_stream [512,128,768]
    const float* Wk = (const float*)d_in[1];   // [768,256]
    const float* Wq = (const float*)d_in[2];
    const float* Wv = (const float*)d_in[3];

    unsigned short* WT  = (unsigned short*)d_ws;          // 768*768 bf16
    unsigned short* QKV = WT + (size_t)768 * 768;         // 512*3*32768 bf16
    float* Out = (float*)d_out;

    prep_w<<<768, 768, 0, stream>>>(Wk, Wq, Wv, WT);
    qkv_gemm<<<768, 512, 0, stream>>>(X, WT, QKV);
    attn<<<512, 512, 0, stream>>>(QKV, Out);
}

// Round 8
// 679.772 us; speedup vs baseline: 1.0958x; 1.0958x over previous
//
#include <hip/hip_runtime.h>
#include <hip/hip_bf16.h>

typedef float f32x4 __attribute__((ext_vector_type(4)));
typedef short bfx8 __attribute__((ext_vector_type(8)));   // 8 bf16 in 4 VGPRs

typedef const __attribute__((address_space(1))) void* gvp;
typedef __attribute__((address_space(3))) void* lvp;

static __device__ __forceinline__ unsigned short f2bf(float f) {
    return __builtin_bit_cast(unsigned short, __float2bfloat16(f));
}

static __device__ __forceinline__ bfx8 cvt8(f32x4 lo, f32x4 hi) {
    bfx8 r;
    r[0] = (short)f2bf(lo[0]); r[1] = (short)f2bf(lo[1]);
    r[2] = (short)f2bf(lo[2]); r[3] = (short)f2bf(lo[3]);
    r[4] = (short)f2bf(hi[0]); r[5] = (short)f2bf(hi[1]);
    r[6] = (short)f2bf(hi[2]); r[7] = (short)f2bf(hi[3]);
    return r;
}

// ---------------------------------------------------------------------------
// Kernel 0: cast + transpose weights into WcatT[768][768] bf16.
// ---------------------------------------------------------------------------
__global__ void prep_w(const float* __restrict__ Wk, const float* __restrict__ Wq,
                       const float* __restrict__ Wv, unsigned short* __restrict__ WT) {
    const int n = blockIdx.x;       // 0..767
    const int e = threadIdx.x;      // 0..767
    const int which = n >> 8;
    const int h = n & 255;
    const float* W = (which == 0) ? Wq : (which == 1) ? Wk : Wv;
    WT[(size_t)n * 768 + e] = f2bf(W[(size_t)e * 256 + h]);
}

// ---------------------------------------------------------------------------
// Kernel 0b: X f32 -> bf16 (memory-bound, vectorized 16B stores).
// Needed so the GEMM can stage A via global_load_lds with ZERO register
// staging (rounds 5-6 post-mortem: areg+acc exceeded the unified 256-reg
// budget at 8 waves -> scratch spill, 1.27GB writes).
// ---------------------------------------------------------------------------
__global__ void cvt_x(const float* __restrict__ X, unsigned short* __restrict__ Xb,
                      long n) {
    long i = ((long)blockIdx.x * 256 + threadIdx.x) * 8;
    const long stride = (long)gridDim.x * 256 * 8;
    for (; i < n; i += stride) {
        f32x4 lo = *(const f32x4*)(X + i);
        f32x4 hi = *(const f32x4*)(X + i + 4);
        *(bfx8*)(Xb + i) = cvt8(lo, hi);
    }
}

// ---------------------------------------------------------------------------
// Kernel 1: QKV = Xb @ [Wq|Wk|Wv].  256x256 tile, 8 waves (2M x 4N), BK=64.
// BOTH operands via global_load_lds w16, linear LDS dest, pre-swizzled
// global source (byte^=(row&7)<<4), swizzled ds_read_b128 (2-way max).
// 2-deep counted-vmcnt pipeline (T4): 16 loads in flight, wait vmcnt(8)
// (= current tile complete, next tile still flying), raw s_barrier.
// Per-wave regs: acc 128 (AGPR) + ~70 arch -> fits 256 budget, no spill.
//  bn 0/1 (Q,K): out [t][h];  bn 2 (V): operand-swapped -> out V'[h][t]
// LDS: A0[0,32K) A1[32K,64K) B0[64K,96K) B1[96K,128K); epilogue reuses all.
// ---------------------------------------------------------------------------
__global__ __launch_bounds__(512) void qkv_gemm(const unsigned short* __restrict__ Xb,
                                                const unsigned short* __restrict__ WT,
                                                unsigned short* __restrict__ QKV,
                                                int b0, int nwg) {
    __shared__ __align__(16) char LDS[131072];

    const int tid = threadIdx.x;
    const int bid = blockIdx.x;
    // bijective XCD remap (m204 general form)
    const int q = nwg >> 3, r = nwg & 7;
    const int xcd = bid & 7, idx = bid >> 3;
    const int l = (xcd < r ? xcd * (q + 1) : r * (q + 1) + (xcd - r) * q) + idx;
    const int bn = l % 3;                          // 0=Q 1=K 2=V
    const int bm = l / 3;
    const int m0 = bm * 256;                       // row offset within Xb chunk
    const int n0 = bn * 256;
    const int w = tid >> 6, lane = tid & 63;
    const int wr = w >> 2, wc = w & 3;             // 2M x 4N wave grid
    const int lrow = lane & 15, lhi = lane >> 4;
    const bool vswap = (bn == 2);

    f32x4 acc[8][4];
    const f32x4 zero = {0.f, 0.f, 0.f, 0.f};
#pragma unroll
    for (int i = 0; i < 8; ++i)
#pragma unroll
        for (int j = 0; j < 4; ++j) acc[i][j] = zero;

    // stage one K-tile (A 32KB + B 32KB) = 8 gload_lds per thread
#define STAGE(kt, bs)                                                          \
    {                                                                          \
        const int k0s = (kt) * 64;                                             \
        _Pragma("unroll")                                                      \
        for (int i = 0; i < 4; ++i) {                                          \
            const int f = i * 512 + tid;                                       \
            const int row = f >> 3;                                            \
            const int cbs = ((f & 7) * 16) ^ ((row & 7) << 4);                 \
            const unsigned short* ga = Xb + (size_t)(m0 + row) * 768 + k0s + (cbs >> 1); \
            char* lpa = LDS + (bs) * 32768 + i * 8192 + tid * 16;              \
            __builtin_amdgcn_global_load_lds((gvp)ga, (lvp)lpa, 16, 0, 0);     \
            const unsigned short* gb = WT + (size_t)(n0 + row) * 768 + k0s + (cbs >> 1); \
            char* lpb = LDS + 65536 + (bs) * 32768 + i * 8192 + tid * 16;      \
            __builtin_amdgcn_global_load_lds((gvp)gb, (lvp)lpb, 16, 0, 0);     \
        }                                                                      \
    }

    STAGE(0, 0);
    STAGE(1, 1);

    int cur = 0;
    for (int kt = 0; kt < 12; ++kt) {
        if (kt < 11) asm volatile("s_waitcnt vmcnt(8)" ::: "memory");
        else         asm volatile("s_waitcnt vmcnt(0)" ::: "memory");
        __builtin_amdgcn_s_barrier();     // tile kt resident for ALL waves
#pragma unroll
        for (int kk = 0; kk < 2; ++kk) {
            const int kb2 = (kk * 32 + lhi * 8) * 2;       // byte col in 128B row
            bfx8 a[8], bb4[4];
#pragma unroll
            for (int ni = 0; ni < 4; ++ni) {
                const int brow = wc * 64 + ni * 16 + lrow;
                bb4[ni] = *(const bfx8*)(LDS + 65536 + cur * 32768 + brow * 128 +
                                         (kb2 ^ ((brow & 7) << 4)));
            }
#pragma unroll
            for (int mi = 0; mi < 8; ++mi) {
                const int arow = wr * 128 + mi * 16 + lrow;
                a[mi] = *(const bfx8*)(LDS + cur * 32768 + arow * 128 +
                                       (kb2 ^ ((arow & 7) << 4)));
            }
            if (!vswap) {
#pragma unroll
                for (int mi = 0; mi < 8; ++mi)
#pragma unroll
                    for (int ni = 0; ni < 4; ++ni)
                        acc[mi][ni] = __builtin_amdgcn_mfma_f32_16x16x32_bf16(
                            a[mi], bb4[ni], acc[mi][ni], 0, 0, 0);
            } else {
#pragma unroll
                for (int mi = 0; mi < 8; ++mi)
#pragma unroll
                    for (int ni = 0; ni < 4; ++ni)
                        acc[mi][ni] = __builtin_amdgcn_mfma_f32_16x16x32_bf16(
                            bb4[ni], a[mi], acc[mi][ni], 0, 0, 0);   // D[n][m]
            }
        }
        __builtin_amdgcn_s_barrier();     // all waves done reading buf[cur]
        if (kt < 10) STAGE(kt + 2, cur);  // overwrite cur with tile kt+2
        cur ^= 1;
    }

    // ---- epilogue: fragments -> swizzled LDS C[256 rows][512B], then
    //      coalesced 16B/lane global stores.
    if (!vswap) {
#pragma unroll
        for (int mi = 0; mi < 8; ++mi)
#pragma unroll
            for (int ni = 0; ni < 4; ++ni) {
                const int h2 = (wc * 64 + ni * 16 + lrow) * 2;
#pragma unroll
                for (int j = 0; j < 4; ++j) {
                    const int trel = wr * 128 + mi * 16 + lhi * 4 + j;
                    *(unsigned short*)(LDS + trel * 512 + (h2 ^ ((trel & 7) << 4))) =
                        f2bf(acc[mi][ni][j]);
                }
            }
    } else {
#pragma unroll
        for (int mi = 0; mi < 8; ++mi)
#pragma unroll
            for (int ni = 0; ni < 4; ++ni) {
                const int t2 = (wr * 128 + mi * 16 + lrow) * 2;
#pragma unroll
                for (int j = 0; j < 4; ++j) {
                    const int h = wc * 64 + ni * 16 + lhi * 4 + j;
                    *(unsigned short*)(LDS + h * 512 + (t2 ^ ((h & 7) << 4))) =
                        f2bf(acc[mi][ni][j]);
                }
            }
    }
    __syncthreads();

#pragma unroll
    for (int i = 0; i < 16; ++i) {
        const int f = i * 512 + tid;
        const int rr = f >> 5;            // LDS row (trel for Q/K, h for V)
        const int c8 = (f & 31) * 8;      // element offset in row
        const bfx8 v = *(const bfx8*)(LDS + rr * 512 + ((c8 * 2) ^ ((rr & 7) << 4)));
        if (bn < 2) {
            const int b = b0 + bm * 2 + (rr >> 7);
            unsigned short* g = QKV + (((size_t)(b * 3 + bn)) << 15) +
                                (size_t)(rr & 127) * 256 + c8;
            *(bfx8*)g = v;
        } else {
            const int b = b0 + bm * 2 + (c8 >> 7);
            unsigned short* g = QKV + (((size_t)(b * 3 + 2)) << 15) +
                                (size_t)rr * 128 + (c8 & 127);
            *(bfx8*)g = v;
        }
    }
}

// ---------------------------------------------------------------------------
// Kernel 2: per-batch causal attention (unchanged — passing).
// ---------------------------------------------------------------------------
__global__ __launch_bounds__(512) void attn(const unsigned short* __restrict__ QKV,
                                            float* __restrict__ Out) {
    __shared__ unsigned short Kl[128][264];
    __shared__ unsigned short Vt[256][136];

    const int b = blockIdx.x;
    const int tid = threadIdx.x;
    const int w = tid >> 6, lane = tid & 63;
    const int lrow = lane & 15, lhi = lane >> 4;

    const unsigned short* Qb = QKV + ((size_t)(b * 3 + 0) << 15);
    const unsigned short* Kb = QKV + ((size_t)(b * 3 + 1) << 15);
    const unsigned short* Vb = QKV + ((size_t)(b * 3 + 2) << 15);

    const int t0 = w * 16;
    bfx8 aq[8];
#pragma unroll
    for (int kk = 0; kk < 8; ++kk)
        aq[kk] = *(const bfx8*)(Qb + (size_t)(t0 + lrow) * 256 + kk * 32 + lhi * 8);

#pragma unroll
    for (int i = 0; i < 8; ++i) {
        int f = i * 512 + tid;
        {
            int row = f >> 5, c = (f & 31) * 8;
            *(bfx8*)&Kl[row][c] = *(const bfx8*)(Kb + (size_t)row * 256 + c);
        }
        {
            int row = f >> 4, c = (f & 15) * 8;
            *(bfx8*)&Vt[row][c] = *(const bfx8*)(Vb + (size_t)row * 128 + c);
        }
    }
    __syncthreads();

    f32x4 sacc[8];
    const f32x4 zero = {0.f, 0.f, 0.f, 0.f};
#pragma unroll
    for (int sj = 0; sj < 8; ++sj) sacc[sj] = zero;
#pragma unroll
    for (int kk = 0; kk < 8; ++kk) {
        const int kb = kk * 32 + lhi * 8;
#pragma unroll
        for (int sj = 0; sj < 8; ++sj) {
            bfx8 bk = *(const bfx8*)&Kl[sj * 16 + lrow][kb];
            sacc[sj] = __builtin_amdgcn_mfma_f32_16x16x32_bf16(aq[kk], bk, sacc[sj], 0, 0, 0);
        }
    }

    const float scale = 0.03608439182435161f;   // 1/sqrt(768)
    float inv[4];
#pragma unroll
    for (int j = 0; j < 4; ++j) {
        const int t = t0 + lhi * 4 + j;
        float m = -1e30f;
#pragma unroll
        for (int sj = 0; sj < 8; ++sj) {
            int s = sj * 16 + lrow;
            float vv = sacc[sj][j] * scale;
            vv = (s <= t) ? vv : -1e30f;
            sacc[sj][j] = vv;
            m = fmaxf(m, vv);
        }
#pragma unroll
        for (int d = 1; d < 16; d <<= 1) m = fmaxf(m, __shfl_xor(m, d));
        float sum = 0.f;
#pragma unroll
        for (int sj = 0; sj < 8; ++sj) {
            float e = __expf(sacc[sj][j] - m);
            sacc[sj][j] = e;
            sum += e;
        }
#pragma unroll
        for (int d = 1; d < 16; d <<= 1) sum += __shfl_xor(sum, d);
        inv[j] = 1.0f / sum;
    }

    __syncthreads();

    unsigned short* Pl = &Kl[0][0] + (size_t)w * (16 * 136);
#pragma unroll
    for (int sj = 0; sj < 8; ++sj)
#pragma unroll
        for (int j = 0; j < 4; ++j)
            Pl[(lhi * 4 + j) * 136 + sj * 16 + lrow] = f2bf(sacc[sj][j] * inv[j]);

    bfx8 pa[4];
#pragma unroll
    for (int kk = 0; kk < 4; ++kk)
        pa[kk] = *(const bfx8*)(Pl + lrow * 136 + kk * 32 + lhi * 8);

    f32x4 oacc[16];
#pragma unroll
    for (int ni = 0; ni < 16; ++ni) oacc[ni] = zero;
#pragma unroll
    for (int ni = 0; ni < 16; ++ni) {
#pragma unroll
        for (int kk = 0; kk < 4; ++kk) {
            bfx8 bv = *(const bfx8*)&Vt[ni * 16 + lrow][kk * 32 + lhi * 8];
            oacc[ni] = __builtin_amdgcn_mfma_f32_16x16x32_bf16(pa[kk], bv, oacc[ni], 0, 0, 0);
        }
    }

    float* Ob = Out + (size_t)b * 128 * 256;
#pragma unroll
    for (int ni = 0; ni < 16; ++ni) {
#pragma unroll
        for (int j = 0; j < 4; ++j) {
            const int t = t0 + lhi * 4 + j;
            const int h = ni * 16 + lrow;
            Ob[(size_t)t * 256 + h] = oacc[ni][j];
        }
    }
}

// ---------------------------------------------------------------------------
extern "C" void kernel_launch(void* const* d_in, const int* in_sizes, int n_in,
                              void* d_out, int out_size, void* d_ws, size_t ws_size,
                              hipStream_t stream) {
    (void)in_sizes; (void)n_in; (void)out_size;
    const float* X  = (const float*)d_in[0];   // res_stream [512,128,768]
    const float* Wk = (const float*)d_in[1];   // [768,256]
    const float* Wq = (const float*)d_in[2];
    const float* Wv = (const float*)d_in[3];

    const size_t WT_E  = (size_t)768 * 768;
    const size_t QKV_E = (size_t)512 * 3 * 32768;
    unsigned short* WT  = (unsigned short*)d_ws;
    unsigned short* QKV = WT + WT_E;
    unsigned short* Xb  = QKV + QKV_E;
    float* Out = (float*)d_out;

    const long perBatch = 128 * 768;                 // elements per batch
    size_t used = (WT_E + QKV_E) * 2;                // bytes
    size_t availB = (ws_size > used) ? ws_size - used : 0;
    int chunk = (int)((availB / 2) / (size_t)perBatch);   // batches that fit
    if (chunk > 512) chunk = 512;
    chunk &= ~1;
    if (chunk < 2) chunk = 2;                        // ws >= 102MB proven; safe

    prep_w<<<768, 768, 0, stream>>>(Wk, Wq, Wv, WT);
    for (int b0 = 0; b0 < 512; b0 += chunk) {
        const int cb = (512 - b0 < chunk) ? (512 - b0) : chunk;
        const long n = (long)cb * perBatch;
        cvt_x<<<1024, 256, 0, stream>>>(X + (size_t)b0 * perBatch, Xb, n);
        const int nwg = (cb / 2) * 3;
        qkv_gemm<<<nwg, 512, 0, stream>>>(Xb, WT, QKV, b0, nwg);
    }
    attn<<<512, 512, 0, stream>>>(QKV, Out);
}

// Round 9
// 218.631 us; speedup vs baseline: 3.4069x; 3.1092x over previous
//
#include <hip/hip_runtime.h>
#include <hip/hip_bf16.h>

typedef float f32x4 __attribute__((ext_vector_type(4)));
typedef short bfx8 __attribute__((ext_vector_type(8)));   // 8 bf16 in 4 VGPRs

typedef const __attribute__((address_space(1))) void* gvp;
typedef __attribute__((address_space(3))) void* lvp;

static __device__ __forceinline__ unsigned short f2bf(float f) {
    return __builtin_bit_cast(unsigned short, __float2bfloat16(f));
}

static __device__ __forceinline__ bfx8 cvt8(f32x4 lo, f32x4 hi) {
    bfx8 r;
    r[0] = (short)f2bf(lo[0]); r[1] = (short)f2bf(lo[1]);
    r[2] = (short)f2bf(lo[2]); r[3] = (short)f2bf(lo[3]);
    r[4] = (short)f2bf(hi[0]); r[5] = (short)f2bf(hi[1]);
    r[6] = (short)f2bf(hi[2]); r[7] = (short)f2bf(hi[3]);
    return r;
}

// ---------------------------------------------------------------------------
// Kernel 0: cast + transpose weights into WcatT[768][768] bf16.
// ---------------------------------------------------------------------------
__global__ void prep_w(const float* __restrict__ Wk, const float* __restrict__ Wq,
                       const float* __restrict__ Wv, unsigned short* __restrict__ WT) {
    const int n = blockIdx.x;       // 0..767
    const int e = threadIdx.x;      // 0..767
    const int which = n >> 8;
    const int h = n & 255;
    const float* W = (which == 0) ? Wq : (which == 1) ? Wk : Wv;
    WT[(size_t)n * 768 + e] = f2bf(W[(size_t)e * 256 + h]);
}

// ---------------------------------------------------------------------------
// Kernel 0b: X f32 -> bf16, vectorized. Moves the convert off the GEMM's
// fragment critical path (r2's limiter) and enables global_load_lds for A.
// ---------------------------------------------------------------------------
__global__ void cvt_x(const float* __restrict__ X, unsigned short* __restrict__ Xb,
                      long n) {
    long i = ((long)blockIdx.x * 256 + threadIdx.x) * 8;
    const long stride = (long)gridDim.x * 256 * 8;
    for (; i < n; i += stride) {
        f32x4 lo = *(const f32x4*)(X + i);
        f32x4 hi = *(const f32x4*)(X + i + 4);
        *(bfx8*)(Xb + i) = cvt8(lo, hi);
    }
}

// ---------------------------------------------------------------------------
// Kernel 1: QKV = Xb @ [Wq|Wk|Wv].  m97-exact structure:
//   128x128 tile, 4 waves (2x2), BK=64, 256 threads, single-buffered 32KB
//   LDS, BOTH operands via global_load_lds w16 (linear dest, pre-swizzled
//   global source byte^=(row&7)<<4), swizzled ds_read_b128 (2-way, free).
// SESSION RULE (r5-r8 post-mortem): 512-thr blocks pin VGPR=128 ->
//   acc[8][4] spills 1.27GB scratch. 256-thr + acc[4][4] = zero scratch.
//   bn 0..3 (Q,K): out [t][h];  bn 4..5 (V): operand-swapped -> V'[h][t]
// ---------------------------------------------------------------------------
__global__ __launch_bounds__(256) void qkv_gemm(const unsigned short* __restrict__ Xb,
                                                const unsigned short* __restrict__ WT,
                                                unsigned short* __restrict__ QKV,
                                                int b0, int nwg) {
    __shared__ unsigned short Ab[128][64];   // 16 KB
    __shared__ unsigned short Bb[128][64];   // 16 KB

    const int tid = threadIdx.x;
    const int bid = blockIdx.x;
    // bijective XCD remap (m204 general form): 6 n-blocks of one X-tile
    // become consecutive on the same XCD (L2 reuse of the A panel).
    const int q = nwg >> 3, r = nwg & 7;
    const int xcd = bid & 7, idx = bid >> 3;
    const int l = (xcd < r ? xcd * (q + 1) : r * (q + 1) + (xcd - r) * q) + idx;
    const int bn = l % 6;                          // 0..3 Q,K halves; 4..5 V
    const int bm = l / 6;                          // batch index within chunk
    const int m0 = bm * 128;
    const int n0 = bn * 128;
    const int w = tid >> 6, lane = tid & 63;
    const int wr = w >> 1, wc = w & 1;
    const int lrow = lane & 15, lhi = lane >> 4;
    const bool vswap = (bn >= 4);

    f32x4 acc[4][4];
    const f32x4 zero = {0.f, 0.f, 0.f, 0.f};
#pragma unroll
    for (int i = 0; i < 4; ++i)
#pragma unroll
        for (int j = 0; j < 4; ++j) acc[i][j] = zero;

    for (int kt = 0; kt < 12; ++kt) {
        const int k0 = kt * 64;
        // stage A (16KB) + B (16KB): 4+4 global_load_lds dwordx4 issues
#pragma unroll
        for (int i = 0; i < 4; ++i) {
            const int f = i * 256 + tid;
            const int row = f >> 3;
            const int cbs = ((f & 7) * 16) ^ ((row & 7) << 4);
            const unsigned short* ga = Xb + (size_t)(m0 + row) * 768 + k0 + (cbs >> 1);
            char* lpa = (char*)&Ab[0][0] + i * 4096 + w * 1024;
            __builtin_amdgcn_global_load_lds((gvp)ga, (lvp)lpa, 16, 0, 0);
            const unsigned short* gb = WT + (size_t)(n0 + row) * 768 + k0 + (cbs >> 1);
            char* lpb = (char*)&Bb[0][0] + i * 4096 + w * 1024;
            __builtin_amdgcn_global_load_lds((gvp)gb, (lvp)lpb, 16, 0, 0);
        }
        __syncthreads();   // drains the staging DMA (vmcnt) for all waves

#pragma unroll
        for (int kk = 0; kk < 2; ++kk) {
            const int kb2 = (kk * 32 + lhi * 8) * 2;       // byte col in 128B row
            bfx8 a[4], bb4[4];
#pragma unroll
            for (int mi = 0; mi < 4; ++mi) {
                const int arow = wr * 64 + mi * 16 + lrow;
                a[mi] = *(const bfx8*)((const char*)&Ab[arow][0] +
                                       (kb2 ^ ((arow & 7) << 4)));
            }
#pragma unroll
            for (int ni = 0; ni < 4; ++ni) {
                const int brow = wc * 64 + ni * 16 + lrow;
                bb4[ni] = *(const bfx8*)((const char*)&Bb[brow][0] +
                                         (kb2 ^ ((brow & 7) << 4)));
            }
            if (!vswap) {
#pragma unroll
                for (int mi = 0; mi < 4; ++mi)
#pragma unroll
                    for (int ni = 0; ni < 4; ++ni)
                        acc[mi][ni] = __builtin_amdgcn_mfma_f32_16x16x32_bf16(
                            a[mi], bb4[ni], acc[mi][ni], 0, 0, 0);
            } else {
#pragma unroll
                for (int ni = 0; ni < 4; ++ni)
#pragma unroll
                    for (int mi = 0; mi < 4; ++mi)
                        acc[ni][mi] = __builtin_amdgcn_mfma_f32_16x16x32_bf16(
                            bb4[ni], a[mi], acc[ni][mi], 0, 0, 0);
            }
        }
        __syncthreads();   // all waves done reading before restage
    }

    // epilogue: direct fragment stores (r2-proven; WRITE_SIZE was legit)
    const int b = b0 + bm;
    if (!vswap) {
        const int which = bn >> 1;                         // 0=Q, 1=K
        const size_t base = ((size_t)(b * 3 + which)) << 15;
        const int hbase = (bn & 1) * 128;
#pragma unroll
        for (int mi = 0; mi < 4; ++mi)
#pragma unroll
            for (int ni = 0; ni < 4; ++ni) {
                const int t = wr * 64 + mi * 16 + lhi * 4;
                const int h = hbase + wc * 64 + ni * 16 + lrow;
#pragma unroll
                for (int j = 0; j < 4; ++j)
                    QKV[base + (size_t)(t + j) * 256 + h] = f2bf(acc[mi][ni][j]);
            }
    } else {
        const size_t base = ((size_t)(b * 3 + 2)) << 15;
#pragma unroll
        for (int ni = 0; ni < 4; ++ni)
#pragma unroll
            for (int mi = 0; mi < 4; ++mi) {
                const int h = (bn - 4) * 128 + wc * 64 + ni * 16 + lhi * 4;
                const int t = wr * 64 + mi * 16 + lrow;
#pragma unroll
                for (int j = 0; j < 4; ++j)
                    QKV[base + (size_t)(h + j) * 128 + t] = f2bf(acc[ni][mi][j]);
            }
    }
}

// ---------------------------------------------------------------------------
// Kernel 2: per-batch causal attention (unchanged — passing).
// ---------------------------------------------------------------------------
__global__ __launch_bounds__(512) void attn(const unsigned short* __restrict__ QKV,
                                            float* __restrict__ Out) {
    __shared__ unsigned short Kl[128][264];
    __shared__ unsigned short Vt[256][136];

    const int b = blockIdx.x;
    const int tid = threadIdx.x;
    const int w = tid >> 6, lane = tid & 63;
    const int lrow = lane & 15, lhi = lane >> 4;

    const unsigned short* Qb = QKV + ((size_t)(b * 3 + 0) << 15);
    const unsigned short* Kb = QKV + ((size_t)(b * 3 + 1) << 15);
    const unsigned short* Vb = QKV + ((size_t)(b * 3 + 2) << 15);

    const int t0 = w * 16;
    bfx8 aq[8];
#pragma unroll
    for (int kk = 0; kk < 8; ++kk)
        aq[kk] = *(const bfx8*)(Qb + (size_t)(t0 + lrow) * 256 + kk * 32 + lhi * 8);

#pragma unroll
    for (int i = 0; i < 8; ++i) {
        int f = i * 512 + tid;
        {
            int row = f >> 5, c = (f & 31) * 8;
            *(bfx8*)&Kl[row][c] = *(const bfx8*)(Kb + (size_t)row * 256 + c);
        }
        {
            int row = f >> 4, c = (f & 15) * 8;
            *(bfx8*)&Vt[row][c] = *(const bfx8*)(Vb + (size_t)row * 128 + c);
        }
    }
    __syncthreads();

    f32x4 sacc[8];
    const f32x4 zero = {0.f, 0.f, 0.f, 0.f};
#pragma unroll
    for (int sj = 0; sj < 8; ++sj) sacc[sj] = zero;
#pragma unroll
    for (int kk = 0; kk < 8; ++kk) {
        const int kb = kk * 32 + lhi * 8;
#pragma unroll
        for (int sj = 0; sj < 8; ++sj) {
            bfx8 bk = *(const bfx8*)&Kl[sj * 16 + lrow][kb];
            sacc[sj] = __builtin_amdgcn_mfma_f32_16x16x32_bf16(aq[kk], bk, sacc[sj], 0, 0, 0);
        }
    }

    const float scale = 0.03608439182435161f;   // 1/sqrt(768)
    float inv[4];
#pragma unroll
    for (int j = 0; j < 4; ++j) {
        const int t = t0 + lhi * 4 + j;
        float m = -1e30f;
#pragma unroll
        for (int sj = 0; sj < 8; ++sj) {
            int s = sj * 16 + lrow;
            float vv = sacc[sj][j] * scale;
            vv = (s <= t) ? vv : -1e30f;
            sacc[sj][j] = vv;
            m = fmaxf(m, vv);
        }
#pragma unroll
        for (int d = 1; d < 16; d <<= 1) m = fmaxf(m, __shfl_xor(m, d));
        float sum = 0.f;
#pragma unroll
        for (int sj = 0; sj < 8; ++sj) {
            float e = __expf(sacc[sj][j] - m);
            sacc[sj][j] = e;
            sum += e;
        }
#pragma unroll
        for (int d = 1; d < 16; d <<= 1) sum += __shfl_xor(sum, d);
        inv[j] = 1.0f / sum;
    }

    __syncthreads();

    unsigned short* Pl = &Kl[0][0] + (size_t)w * (16 * 136);
#pragma unroll
    for (int sj = 0; sj < 8; ++sj)
#pragma unroll
        for (int j = 0; j < 4; ++j)
            Pl[(lhi * 4 + j) * 136 + sj * 16 + lrow] = f2bf(sacc[sj][j] * inv[j]);

    bfx8 pa[4];
#pragma unroll
    for (int kk = 0; kk < 4; ++kk)
        pa[kk] = *(const bfx8*)(Pl + lrow * 136 + kk * 32 + lhi * 8);

    f32x4 oacc[16];
#pragma unroll
    for (int ni = 0; ni < 16; ++ni) oacc[ni] = zero;
#pragma unroll
    for (int ni = 0; ni < 16; ++ni) {
#pragma unroll
        for (int kk = 0; kk < 4; ++kk) {
            bfx8 bv = *(const bfx8*)&Vt[ni * 16 + lrow][kk * 32 + lhi * 8];
            oacc[ni] = __builtin_amdgcn_mfma_f32_16x16x32_bf16(pa[kk], bv, oacc[ni], 0, 0, 0);
        }
    }

    float* Ob = Out + (size_t)b * 128 * 256;
#pragma unroll
    for (int ni = 0; ni < 16; ++ni) {
#pragma unroll
        for (int j = 0; j < 4; ++j) {
            const int t = t0 + lhi * 4 + j;
            const int h = ni * 16 + lrow;
            Ob[(size_t)t * 256 + h] = oacc[ni][j];
        }
    }
}

// ---------------------------------------------------------------------------
extern "C" void kernel_launch(void* const* d_in, const int* in_sizes, int n_in,
                              void* d_out, int out_size, void* d_ws, size_t ws_size,
                              hipStream_t stream) {
    (void)in_sizes; (void)n_in; (void)out_size;
    const float* X  = (const float*)d_in[0];   // res_stream [512,128,768]
    const float* Wk = (const float*)d_in[1];   // [768,256]
    const float* Wq = (const float*)d_in[2];
    const float* Wv = (const float*)d_in[3];

    const size_t WT_E  = (size_t)768 * 768;
    const size_t QKV_E = (size_t)512 * 3 * 32768;
    unsigned short* WT  = (unsigned short*)d_ws;
    unsigned short* QKV = WT + WT_E;
    unsigned short* Xb  = QKV + QKV_E;
    float* Out = (float*)d_out;

    const long perBatch = 128 * 768;                 // elements per batch
    size_t used = (WT_E + QKV_E) * 2;                // bytes
    size_t availB = (ws_size > used) ? ws_size - used : 0;
    int chunk = (int)((availB / 2) / (size_t)perBatch);   // batches that fit
    if (chunk > 512) chunk = 512;
    if (chunk < 1) chunk = 1;                        // ws >= 203MB proven (r8)

    prep_w<<<768, 768, 0, stream>>>(Wk, Wq, Wv, WT);
    for (int b0 = 0; b0 < 512; b0 += chunk) {
        const int cb = (512 - b0 < chunk) ? (512 - b0) : chunk;
        const long n = (long)cb * perBatch;
        cvt_x<<<2048, 256, 0, stream>>>(X + (size_t)b0 * perBatch, Xb, n);
        const int nwg = cb * 6;
        qkv_gemm<<<nwg, 256, 0, stream>>>(Xb, WT, QKV, b0, nwg);
    }
    attn<<<512, 512, 0, stream>>>(QKV, Out);
}

// Round 10
// 198.874 us; speedup vs baseline: 3.7454x; 1.0993x over previous
//
#include <hip/hip_runtime.h>
#include <hip/hip_bf16.h>

typedef float f32x4 __attribute__((ext_vector_type(4)));
typedef short bfx8 __attribute__((ext_vector_type(8)));   // 8 bf16 in 4 VGPRs

typedef const __attribute__((address_space(1))) void* gvp;
typedef __attribute__((address_space(3))) void* lvp;

static __device__ __forceinline__ unsigned short f2bf(float f) {
    return __builtin_bit_cast(unsigned short, __float2bfloat16(f));
}

static __device__ __forceinline__ bfx8 cvt8(f32x4 lo, f32x4 hi) {
    bfx8 r;
    r[0] = (short)f2bf(lo[0]); r[1] = (short)f2bf(lo[1]);
    r[2] = (short)f2bf(lo[2]); r[3] = (short)f2bf(lo[3]);
    r[4] = (short)f2bf(hi[0]); r[5] = (short)f2bf(hi[1]);
    r[6] = (short)f2bf(hi[2]); r[7] = (short)f2bf(hi[3]);
    return r;
}

// ---------------------------------------------------------------------------
// Kernel 0: cast + transpose weights into WcatT[768][768] bf16.
// ---------------------------------------------------------------------------
__global__ void prep_w(const float* __restrict__ Wk, const float* __restrict__ Wq,
                       const float* __restrict__ Wv, unsigned short* __restrict__ WT) {
    const int n = blockIdx.x;       // 0..767
    const int e = threadIdx.x;      // 0..767
    const int which = n >> 8;
    const int h = n & 255;
    const float* W = (which == 0) ? Wq : (which == 1) ? Wk : Wv;
    WT[(size_t)n * 768 + e] = f2bf(W[(size_t)e * 256 + h]);
}

// ---------------------------------------------------------------------------
// Kernel 0b: X f32 -> bf16, vectorized (memory-bound, ~48µs floor).
// ---------------------------------------------------------------------------
__global__ void cvt_x(const float* __restrict__ X, unsigned short* __restrict__ Xb,
                      long n) {
    long i = ((long)blockIdx.x * 256 + threadIdx.x) * 8;
    const long stride = (long)gridDim.x * 256 * 8;
    for (; i < n; i += stride) {
        f32x4 lo = *(const f32x4*)(X + i);
        f32x4 hi = *(const f32x4*)(X + i + 4);
        *(bfx8*)(Xb + i) = cvt8(lo, hi);
    }
}

// ---------------------------------------------------------------------------
// Kernel 1: QKV = Xb @ [Wq|Wk|Wv].  128x128 tile, 4 waves, BK=64, 256 thr.
// ROUND 10: 2-deep counted-vmcnt pipeline (T4, r8-refchecked loop structure)
// on the r9 no-spill geometry. Double-buffered 64KB LDS; steady state keeps
// 16 global_load_lds in flight, waits vmcnt(8) (current tile resident, next
// tile flying) -- never drains to 0 until the last K-step.
// SESSION RULE: 256 threads + acc[4][4] only (512-thr pins VGPR=128 -> spill).
//   bn 0..3 (Q,K): out [t][h];  bn 4..5 (V): operand-swapped -> V'[h][t]
// LDS map: A0 [0,16K) A1 [16K,32K) B0 [32K,48K) B1 [48K,64K)
// ---------------------------------------------------------------------------
__global__ __launch_bounds__(256) void qkv_gemm(const unsigned short* __restrict__ Xb,
                                                const unsigned short* __restrict__ WT,
                                                unsigned short* __restrict__ QKV,
                                                int b0, int nwg) {
    __shared__ __align__(16) char LDS[65536];

    const int tid = threadIdx.x;
    const int bid = blockIdx.x;
    // bijective XCD remap (m204): 6 n-blocks of one X-tile stay on one XCD
    const int q = nwg >> 3, r = nwg & 7;
    const int xcd = bid & 7, idx = bid >> 3;
    const int l = (xcd < r ? xcd * (q + 1) : r * (q + 1) + (xcd - r) * q) + idx;
    const int bn = l % 6;                          // 0..3 Q,K halves; 4..5 V
    const int bm = l / 6;                          // batch index within chunk
    const int m0 = bm * 128;
    const int n0 = bn * 128;
    const int w = tid >> 6, lane = tid & 63;
    const int wr = w >> 1, wc = w & 1;
    const int lrow = lane & 15, lhi = lane >> 4;
    const bool vswap = (bn >= 4);

    f32x4 acc[4][4];
    const f32x4 zero = {0.f, 0.f, 0.f, 0.f};
#pragma unroll
    for (int i = 0; i < 4; ++i)
#pragma unroll
        for (int j = 0; j < 4; ++j) acc[i][j] = zero;

    // stage one K-tile (A 16KB + B 16KB) = 8 global_load_lds issues
#define STAGE(kt, bs)                                                          \
    {                                                                          \
        const int k0s = (kt) * 64;                                             \
        _Pragma("unroll")                                                      \
        for (int i = 0; i < 4; ++i) {                                          \
            const int f = i * 256 + tid;                                       \
            const int row = f >> 3;                                            \
            const int cbs = ((f & 7) * 16) ^ ((row & 7) << 4);                 \
            const unsigned short* ga = Xb + (size_t)(m0 + row) * 768 + k0s + (cbs >> 1); \
            char* lpa = LDS + (bs) * 16384 + i * 4096 + w * 1024;              \
            __builtin_amdgcn_global_load_lds((gvp)ga, (lvp)lpa, 16, 0, 0);     \
            const unsigned short* gb = WT + (size_t)(n0 + row) * 768 + k0s + (cbs >> 1); \
            char* lpb = LDS + 32768 + (bs) * 16384 + i * 4096 + w * 1024;      \
            __builtin_amdgcn_global_load_lds((gvp)gb, (lvp)lpb, 16, 0, 0);     \
        }                                                                      \
    }

    STAGE(0, 0);
    STAGE(1, 1);

    int cur = 0;
    for (int kt = 0; kt < 12; ++kt) {
        if (kt < 11) asm volatile("s_waitcnt vmcnt(8)" ::: "memory");
        else         asm volatile("s_waitcnt vmcnt(0)" ::: "memory");
        __builtin_amdgcn_s_barrier();     // tile kt resident for ALL waves
#pragma unroll
        for (int kk = 0; kk < 2; ++kk) {
            const int kb2 = (kk * 32 + lhi * 8) * 2;       // byte col in 128B row
            bfx8 a[4], bb4[4];
#pragma unroll
            for (int mi = 0; mi < 4; ++mi) {
                const int arow = wr * 64 + mi * 16 + lrow;
                a[mi] = *(const bfx8*)(LDS + cur * 16384 + arow * 128 +
                                       (kb2 ^ ((arow & 7) << 4)));
            }
#pragma unroll
            for (int ni = 0; ni < 4; ++ni) {
                const int brow = wc * 64 + ni * 16 + lrow;
                bb4[ni] = *(const bfx8*)(LDS + 32768 + cur * 16384 + brow * 128 +
                                         (kb2 ^ ((brow & 7) << 4)));
            }
            if (!vswap) {
#pragma unroll
                for (int mi = 0; mi < 4; ++mi)
#pragma unroll
                    for (int ni = 0; ni < 4; ++ni)
                        acc[mi][ni] = __builtin_amdgcn_mfma_f32_16x16x32_bf16(
                            a[mi], bb4[ni], acc[mi][ni], 0, 0, 0);
            } else {
#pragma unroll
                for (int ni = 0; ni < 4; ++ni)
#pragma unroll
                    for (int mi = 0; mi < 4; ++mi)
                        acc[ni][mi] = __builtin_amdgcn_mfma_f32_16x16x32_bf16(
                            bb4[ni], a[mi], acc[ni][mi], 0, 0, 0);
            }
        }
        __builtin_amdgcn_s_barrier();     // all waves done reading buf[cur]
        if (kt < 10) STAGE(kt + 2, cur);  // refill retired buffer
        cur ^= 1;
    }

    // epilogue: direct fragment stores (r2/r9-proven; write size is legit)
    const int b = b0 + bm;
    if (!vswap) {
        const int which = bn >> 1;                         // 0=Q, 1=K
        const size_t base = ((size_t)(b * 3 + which)) << 15;
        const int hbase = (bn & 1) * 128;
#pragma unroll
        for (int mi = 0; mi < 4; ++mi)
#pragma unroll
            for (int ni = 0; ni < 4; ++ni) {
                const int t = wr * 64 + mi * 16 + lhi * 4;
                const int h = hbase + wc * 64 + ni * 16 + lrow;
#pragma unroll
                for (int j = 0; j < 4; ++j)
                    QKV[base + (size_t)(t + j) * 256 + h] = f2bf(acc[mi][ni][j]);
            }
    } else {
        const size_t base = ((size_t)(b * 3 + 2)) << 15;
#pragma unroll
        for (int ni = 0; ni < 4; ++ni)
#pragma unroll
            for (int mi = 0; mi < 4; ++mi) {
                const int h = (bn - 4) * 128 + wc * 64 + ni * 16 + lhi * 4;
                const int t = wr * 64 + mi * 16 + lrow;
#pragma unroll
                for (int j = 0; j < 4; ++j)
                    QKV[base + (size_t)(h + j) * 128 + t] = f2bf(acc[ni][mi][j]);
            }
    }
}

// ---------------------------------------------------------------------------
// Kernel 2: per-batch causal attention (unchanged — passing).
// ---------------------------------------------------------------------------
__global__ __launch_bounds__(512) void attn(const unsigned short* __restrict__ QKV,
                                            float* __restrict__ Out) {
    __shared__ unsigned short Kl[128][264];
    __shared__ unsigned short Vt[256][136];

    const int b = blockIdx.x;
    const int tid = threadIdx.x;
    const int w = tid >> 6, lane = tid & 63;
    const int lrow = lane & 15, lhi = lane >> 4;

    const unsigned short* Qb = QKV + ((size_t)(b * 3 + 0) << 15);
    const unsigned short* Kb = QKV + ((size_t)(b * 3 + 1) << 15);
    const unsigned short* Vb = QKV + ((size_t)(b * 3 + 2) << 15);

    const int t0 = w * 16;
    bfx8 aq[8];
#pragma unroll
    for (int kk = 0; kk < 8; ++kk)
        aq[kk] = *(const bfx8*)(Qb + (size_t)(t0 + lrow) * 256 + kk * 32 + lhi * 8);

#pragma unroll
    for (int i = 0; i < 8; ++i) {
        int f = i * 512 + tid;
        {
            int row = f >> 5, c = (f & 31) * 8;
            *(bfx8*)&Kl[row][c] = *(const bfx8*)(Kb + (size_t)row * 256 + c);
        }
        {
            int row = f >> 4, c = (f & 15) * 8;
            *(bfx8*)&Vt[row][c] = *(const bfx8*)(Vb + (size_t)row * 128 + c);
        }
    }
    __syncthreads();

    f32x4 sacc[8];
    const f32x4 zero = {0.f, 0.f, 0.f, 0.f};
#pragma unroll
    for (int sj = 0; sj < 8; ++sj) sacc[sj] = zero;
#pragma unroll
    for (int kk = 0; kk < 8; ++kk) {
        const int kb = kk * 32 + lhi * 8;
#pragma unroll
        for (int sj = 0; sj < 8; ++sj) {
            bfx8 bk = *(const bfx8*)&Kl[sj * 16 + lrow][kb];
            sacc[sj] = __builtin_amdgcn_mfma_f32_16x16x32_bf16(aq[kk], bk, sacc[sj], 0, 0, 0);
        }
    }

    const float scale = 0.03608439182435161f;   // 1/sqrt(768)
    float inv[4];
#pragma unroll
    for (int j = 0; j < 4; ++j) {
        const int t = t0 + lhi * 4 + j;
        float m = -1e30f;
#pragma unroll
        for (int sj = 0; sj < 8; ++sj) {
            int s = sj * 16 + lrow;
            float vv = sacc[sj][j] * scale;
            vv = (s <= t) ? vv : -1e30f;
            sacc[sj][j] = vv;
            m = fmaxf(m, vv);
        }
#pragma unroll
        for (int d = 1; d < 16; d <<= 1) m = fmaxf(m, __shfl_xor(m, d));
        float sum = 0.f;
#pragma unroll
        for (int sj = 0; sj < 8; ++sj) {
            float e = __expf(sacc[sj][j] - m);
            sacc[sj][j] = e;
            sum += e;
        }
#pragma unroll
        for (int d = 1; d < 16; d <<= 1) sum += __shfl_xor(sum, d);
        inv[j] = 1.0f / sum;
    }

    __syncthreads();

    unsigned short* Pl = &Kl[0][0] + (size_t)w * (16 * 136);
#pragma unroll
    for (int sj = 0; sj < 8; ++sj)
#pragma unroll
        for (int j = 0; j < 4; ++j)
            Pl[(lhi * 4 + j) * 136 + sj * 16 + lrow] = f2bf(sacc[sj][j] * inv[j]);

    bfx8 pa[4];
#pragma unroll
    for (int kk = 0; kk < 4; ++kk)
        pa[kk] = *(const bfx8*)(Pl + lrow * 136 + kk * 32 + lhi * 8);

    f32x4 oacc[16];
#pragma unroll
    for (int ni = 0; ni < 16; ++ni) oacc[ni] = zero;
#pragma unroll
    for (int ni = 0; ni < 16; ++ni) {
#pragma unroll
        for (int kk = 0; kk < 4; ++kk) {
            bfx8 bv = *(const bfx8*)&Vt[ni * 16 + lrow][kk * 32 + lhi * 8];
            oacc[ni] = __builtin_amdgcn_mfma_f32_16x16x32_bf16(pa[kk], bv, oacc[ni], 0, 0, 0);
        }
    }

    float* Ob = Out + (size_t)b * 128 * 256;
#pragma unroll
    for (int ni = 0; ni < 16; ++ni) {
#pragma unroll
        for (int j = 0; j < 4; ++j) {
            const int t = t0 + lhi * 4 + j;
            const int h = ni * 16 + lrow;
            Ob[(size_t)t * 256 + h] = oacc[ni][j];
        }
    }
}

// ---------------------------------------------------------------------------
extern "C" void kernel_launch(void* const* d_in, const int* in_sizes, int n_in,
                              void* d_out, int out_size, void* d_ws, size_t ws_size,
                              hipStream_t stream) {
    (void)in_sizes; (void)n_in; (void)out_size;
    const float* X  = (const float*)d_in[0];   // res_stream [512,128,768]
    const float* Wk = (const float*)d_in[1];   // [768,256]
    const float* Wq = (const float*)d_in[2];
    const float* Wv = (const float*)d_in[3];

    const size_t WT_E  = (size_t)768 * 768;
    const size_t QKV_E = (size_t)512 * 3 * 32768;
    unsigned short* WT  = (unsigned short*)d_ws;
    unsigned short* QKV = WT + WT_E;
    unsigned short* Xb  = QKV + QKV_E;
    float* Out = (float*)d_out;

    const long perBatch = 128 * 768;                 // elements per batch
    size_t used = (WT_E + QKV_E) * 2;                // bytes
    size_t availB = (ws_size > used) ? ws_size - used : 0;
    int chunk = (int)((availB / 2) / (size_t)perBatch);   // batches that fit
    if (chunk > 512) chunk = 512;
    if (chunk < 1) chunk = 1;

    prep_w<<<768, 768, 0, stream>>>(Wk, Wq, Wv, WT);
    for (int b0 = 0; b0 < 512; b0 += chunk) {
        const int cb = (512 - b0 < chunk) ? (512 - b0) : chunk;
        const long n = (long)cb * perBatch;
        cvt_x<<<2048, 256, 0, stream>>>(X + (size_t)b0 * perBatch, Xb, n);
        const int nwg = cb * 6;
        qkv_gemm<<<nwg, 256, 0, stream>>>(Xb, WT, QKV, b0, nwg);
    }
    attn<<<512, 512, 0, stream>>>(QKV, Out);
}